// Round 2
// baseline (90.229 us; speedup 1.0000x reference)
//
#include <hip/hip_runtime.h>

#define CH    512
#define BATCH 16
#define HW    3136     // 56*56
#define HW4   784      // HW/4 (float4 per image plane)
#define THRESH 8.0f

// ---- Kernel 1: per-channel max|x| over (B,H,W) --------------------------
__global__ __launch_bounds__(256) void absmax_kernel(const float* __restrict__ x,
                                                     float* __restrict__ maxv) {
    const int c   = blockIdx.x;       // channel
    const int tid = threadIdx.x;
    const float4* x4 = reinterpret_cast<const float4*>(x);
    float m = 0.0f;
    for (int idx = tid; idx < BATCH * HW4; idx += 256) {
        int bb = idx / HW4;
        int p  = idx - bb * HW4;
        float4 v = x4[(size_t)(bb * CH + c) * HW4 + p];
        m = fmaxf(m, fmaxf(fmaxf(fabsf(v.x), fabsf(v.y)),
                           fmaxf(fabsf(v.z), fabsf(v.w))));
    }
    __shared__ float sm[256];
    sm[tid] = m;
    __syncthreads();
    for (int off = 128; off > 0; off >>= 1) {
        if (tid < off) sm[tid] = fmaxf(sm[tid], sm[tid + off]);
        __syncthreads();
    }
    if (tid == 0) maxv[c] = sm[0];
}

// ---- Kernel 2: build per-outlier plan ----------------------------------
// Outputs (compressed, indexed by outlier ordinal o):
//   oc[o]     = channel id
//   ostart[o] = first output-channel slot for this channel
//   oT[o]     = replication count T
//   oscale[o] = 1/T (f64->f32, matching numpy)
// Also writes the outlier channel ids as fp32 into the output tail.
__global__ __launch_bounds__(CH) void plan_kernel(const float* __restrict__ maxv,
                                                  int*   __restrict__ oc,
                                                  int*   __restrict__ ostart,
                                                  int*   __restrict__ oT,
                                                  float* __restrict__ oscale,
                                                  float* __restrict__ out_tail) {
    const int t = threadIdx.x;        // one thread per channel (512)
    float m = maxv[t];
    int T = 0;
    if (m > THRESH) T = (int)ceilf(m * 0.125f);   // ceil(m/8), /8 exact
    int isout = (T > 0) ? 1 : 0;

    __shared__ int sT[CH];
    __shared__ int sO[CH];
    sT[t] = T;
    sO[t] = isout;
    __syncthreads();
    // Hillis-Steele inclusive scan
    for (int off = 1; off < CH; off <<= 1) {
        int a = 0, b = 0;
        if (t >= off) { a = sT[t - off]; b = sO[t - off]; }
        __syncthreads();
        sT[t] += a;
        sO[t] += b;
        __syncthreads();
    }
    if (T > 0) {
        int s = sT[t] - T;      // exclusive prefix of T -> start slot
        int o = sO[t] - isout;  // outlier ordinal
        oc[o]     = t;
        ostart[o] = s;
        oT[o]     = T;
        oscale[o] = (float)(1.0 / (double)T);
        out_tail[o] = (float)t;
    }
}

// ---- Kernel 3: read plane once, write T scaled replicas -----------------
__global__ __launch_bounds__(256) void gather_kernel(const float* __restrict__ x,
                                                     const int*   __restrict__ oc,
                                                     const int*   __restrict__ ostart,
                                                     const int*   __restrict__ oT,
                                                     const float* __restrict__ oscale,
                                                     float* __restrict__ out,
                                                     int R) {
    const int o = blockIdx.x;   // outlier ordinal
    const int b = blockIdx.y;   // batch
    const int c  = oc[o];       // wave-uniform -> scalar loads
    const int s0 = ostart[o];
    const int T  = oT[o];
    const float sc = oscale[o];
    const float4* src = reinterpret_cast<const float4*>(x)
                        + (size_t)(b * CH + c) * HW4;
    float4* dst = reinterpret_cast<float4*>(out)
                  + ((size_t)b * R + s0) * HW4;
    for (int p = threadIdx.x; p < HW4; p += 256) {
        float4 v = src[p];
        v.x *= sc; v.y *= sc; v.z *= sc; v.w *= sc;
        for (int k = 0; k < T; ++k) {
            dst[(size_t)k * HW4 + p] = v;   // replicas are adjacent planes
        }
    }
}

extern "C" void kernel_launch(void* const* d_in, const int* in_sizes, int n_in,
                              void* d_out, int out_size, void* d_ws, size_t ws_size,
                              hipStream_t stream) {
    const float* x = (const float*)d_in[0];
    float* out = (float*)d_out;

    // out_size = 50176*R + n_out,  n_out <= 512 < 50176  -> unique split
    const int plane = BATCH * HW;               // 50176
    const int R     = out_size / plane;         // total replicated channels
    const int n_out = out_size - R * plane;     // number of outlier channels

    // workspace layout (all tiny):
    float* maxv   = (float*)d_ws;
    int*   oc     = (int*)  ((char*)d_ws + 1 * CH * 4);
    int*   ostart = (int*)  ((char*)d_ws + 2 * CH * 4);
    int*   oT     = (int*)  ((char*)d_ws + 3 * CH * 4);
    float* oscale = (float*)((char*)d_ws + 4 * CH * 4);

    absmax_kernel<<<CH, 256, 0, stream>>>(x, maxv);
    plan_kernel<<<1, CH, 0, stream>>>(maxv, oc, ostart, oT, oscale,
                                      out + (size_t)R * plane);
    if (n_out > 0) {
        gather_kernel<<<dim3(n_out, BATCH), 256, 0, stream>>>(
            x, oc, ostart, oT, oscale, out, R);
    }
}

// Round 3
// 71.117 us; speedup vs baseline: 1.2687x; 1.2687x over previous
//
#include <hip/hip_runtime.h>

#define CH    512
#define BATCH 16
#define HW    3136     // 56*56
#define HW4   784      // HW/4 (float4 per image plane)
#define THRESH 8.0f

typedef float f4 __attribute__((ext_vector_type(4)));

// ---- Kernel 1: per-(channel,batch) plane max|x| -> partial[c*16+b] ------
__global__ __launch_bounds__(256) void absmax_kernel(const float* __restrict__ x,
                                                     float* __restrict__ partial) {
    const int c   = blockIdx.x;       // channel
    const int b   = blockIdx.y;       // batch
    const int tid = threadIdx.x;
    const f4* src = reinterpret_cast<const f4*>(x) + (size_t)(b * CH + c) * HW4;
    float m = 0.0f;
    for (int p = tid; p < HW4; p += 256) {
        f4 v = src[p];
        m = fmaxf(m, fmaxf(fmaxf(fabsf(v.x), fabsf(v.y)),
                           fmaxf(fabsf(v.z), fabsf(v.w))));
    }
    __shared__ float sm[256];
    sm[tid] = m;
    __syncthreads();
    for (int off = 128; off > 0; off >>= 1) {
        if (tid < off) sm[tid] = fmaxf(sm[tid], sm[tid + off]);
        __syncthreads();
    }
    if (tid == 0) partial[c * BATCH + b] = sm[0];
}

// ---- Kernel 2: finish max, build plan (rep idx, 1/T, outlier tail) ------
__global__ __launch_bounds__(CH) void plan_kernel(const float* __restrict__ partial,
                                                  int*   __restrict__ rep,
                                                  float* __restrict__ invT,
                                                  float* __restrict__ out_tail) {
    const int t = threadIdx.x;        // one thread per channel (512)
    float m = 0.0f;
    #pragma unroll
    for (int k = 0; k < BATCH; ++k) m = fmaxf(m, partial[t * BATCH + k]);

    int T = 0;
    if (m > THRESH) T = (int)ceilf(m * 0.125f);   // ceil(m/8), /8 exact in fp32
    int isout = (T > 0) ? 1 : 0;

    __shared__ int sT[CH];
    __shared__ int sO[CH];
    sT[t] = T;
    sO[t] = isout;
    __syncthreads();
    for (int off = 1; off < CH; off <<= 1) {      // Hillis-Steele inclusive scan
        int a = 0, bb = 0;
        if (t >= off) { a = sT[t - off]; bb = sO[t - off]; }
        __syncthreads();
        sT[t] += a;
        sO[t] += bb;
        __syncthreads();
    }
    if (T > 0) {
        int s = sT[t] - T;      // exclusive prefix of T -> start slot in rep
        int o = sO[t] - isout;  // outlier ordinal
        out_tail[o] = (float)t; // outlier channel id as fp32 (flat fp32 d_out)
        float iv = (float)(1.0 / (double)T);   // match numpy f64->f32 rounding
        for (int k = 0; k < T; ++k) {
            rep[s + k]  = t;
            invT[s + k] = iv;
        }
    }
}

// ---- Kernel 3: gather + scale, nontemporal stores, XCD-chunked swizzle --
__global__ __launch_bounds__(256) void gather_kernel(const float* __restrict__ x,
                                                     const int*   __restrict__ rep,
                                                     const float* __restrict__ invT,
                                                     float* __restrict__ out,
                                                     int R) {
    // bijective XCD chunk mapping (8 XCDs): neighbor output-channels j stay
    // on the same XCD so replica re-reads hit that XCD's L2.
    const int nwg  = gridDim.x;
    const int orig = blockIdx.x;
    const int xcd  = orig & 7;
    const int q = nwg >> 3, r = nwg & 7;
    const int wg = (xcd < r ? xcd * (q + 1) : r * (q + 1) + (xcd - r) * q)
                   + (orig >> 3);
    const int j = wg >> 4;        // output channel (BATCH = 16)
    const int b = wg & 15;        // batch

    const int   c = rep[j];       // wave-uniform
    const float s = invT[j];
    const f4* src = reinterpret_cast<const f4*>(x) + (size_t)(b * CH + c) * HW4;
    f4* dst = reinterpret_cast<f4*>(out) + ((size_t)b * R + j) * HW4;
    for (int p = threadIdx.x; p < HW4; p += 256) {
        f4 v = src[p];
        v.x *= s; v.y *= s; v.z *= s; v.w *= s;
        __builtin_nontemporal_store(v, &dst[p]);  // never re-read: keep x in L3
    }
}

extern "C" void kernel_launch(void* const* d_in, const int* in_sizes, int n_in,
                              void* d_out, int out_size, void* d_ws, size_t ws_size,
                              hipStream_t stream) {
    const float* x = (const float*)d_in[0];
    float* out = (float*)d_out;

    // out_size = 50176*R + n_out,  n_out <= 512 < 50176  -> unique split
    const int plane = BATCH * HW;               // 50176
    const int R     = out_size / plane;         // total replicated channels
    const int n_out = out_size - R * plane;     // number of outlier channels
    (void)n_out;

    // workspace: [CH*BATCH floats partial][R ints rep][R floats invT]
    float* partial = (float*)d_ws;
    int*   rep  = (int*)  ((char*)d_ws + (size_t)CH * BATCH * 4);
    float* invT = (float*)((char*)d_ws + (size_t)CH * BATCH * 4 + (size_t)R * 4);

    absmax_kernel<<<dim3(CH, BATCH), 256, 0, stream>>>(x, partial);
    plan_kernel<<<1, CH, 0, stream>>>(partial, rep, invT, out + (size_t)R * plane);
    if (R > 0) {
        gather_kernel<<<dim3(R * BATCH), 256, 0, stream>>>(x, rep, invT, out, R);
    }
}